// Round 1
// baseline (770.642 us; speedup 1.0000x reference)
//
#include <hip/hip_runtime.h>
#include <hip/hip_bf16.h>

// Problem constants (fixed by the reference's setup_inputs).
constexpr int VOCAB    = 32000;
constexpr int NUM_NEW  = 512;
constexpr int HIDDEN   = 4096;
constexpr int PROF_DIM = 64;
constexpr int MLP_HID  = 256;

constexpr int TOK_PER_BLK  = 8;    // tool tokens per block in build_combined
constexpr int COLS_PER_BLK = 512;  // 256 threads x 2 cols

typedef float f32x4 __attribute__((ext_vector_type(4)));

// ---------------------------------------------------------------------------
// Kernel A: combined[rel][:] = tool_semantics[rel] + relu(prof[rel]@W1+b1)@W2 + b2
// Grid: (HIDDEN/COLS_PER_BLK, NUM_NEW/TOK_PER_BLK) = (8, 64); block = 256.
// ---------------------------------------------------------------------------
__global__ __launch_bounds__(256) void build_combined_kernel(
    const float* __restrict__ tool_semantics,  // [NUM_NEW, HIDDEN]
    const float* __restrict__ profiles,        // [NUM_NEW, PROF_DIM]
    const float* __restrict__ W1,              // [PROF_DIM, MLP_HID]
    const float* __restrict__ b1,              // [MLP_HID]
    const float* __restrict__ W2,              // [MLP_HID, HIDDEN]
    const float* __restrict__ b2,              // [HIDDEN]
    float* __restrict__ combined)              // [NUM_NEW, HIDDEN]
{
    __shared__ float prof_s[TOK_PER_BLK][PROF_DIM];  // 2 KiB
    __shared__ float h_s[TOK_PER_BLK][MLP_HID];      // 8 KiB

    const int t    = threadIdx.x;                 // 0..255
    const int tok0 = blockIdx.y * TOK_PER_BLK;    // tool-token group base
    const int col0 = blockIdx.x * COLS_PER_BLK;   // output column base

    // Stage this group's profile rows into LDS (8*64 = 512 floats).
    for (int i = t; i < TOK_PER_BLK * PROF_DIM; i += 256) {
        const int tok = i / PROF_DIM;
        const int p   = i % PROF_DIM;
        prof_s[tok][p] = profiles[(tok0 + tok) * PROF_DIM + p];
    }
    __syncthreads();

    // Layer 1: thread t computes h[tok][t] for all 8 tokens.
    // W1[p][t] reads are coalesced across t; W1 is read once per block.
    {
        float acc[TOK_PER_BLK];
        const float bias = b1[t];
#pragma unroll
        for (int tok = 0; tok < TOK_PER_BLK; ++tok) acc[tok] = bias;
        for (int p = 0; p < PROF_DIM; ++p) {
            const float w = W1[p * MLP_HID + t];
#pragma unroll
            for (int tok = 0; tok < TOK_PER_BLK; ++tok)
                acc[tok] = fmaf(prof_s[tok][p], w, acc[tok]);
        }
#pragma unroll
        for (int tok = 0; tok < TOK_PER_BLK; ++tok)
            h_s[tok][t] = fmaxf(acc[tok], 0.0f);
    }
    __syncthreads();

    // Layer 2: thread t owns columns (c, c+1); accumulate over MLP_HID.
    // h_s[tok][k] is the same address for all lanes -> LDS broadcast (free).
    const int c = col0 + t * 2;
    float2 acc2[TOK_PER_BLK];
#pragma unroll
    for (int tok = 0; tok < TOK_PER_BLK; ++tok) acc2[tok] = make_float2(0.f, 0.f);

    for (int k = 0; k < MLP_HID; ++k) {
        const float2 w2 = *(const float2*)&W2[k * HIDDEN + c];
#pragma unroll
        for (int tok = 0; tok < TOK_PER_BLK; ++tok) {
            const float hv = h_s[tok][k];
            acc2[tok].x = fmaf(hv, w2.x, acc2[tok].x);
            acc2[tok].y = fmaf(hv, w2.y, acc2[tok].y);
        }
    }

    const float2 bias2 = *(const float2*)&b2[c];
#pragma unroll
    for (int tok = 0; tok < TOK_PER_BLK; ++tok) {
        const float2 sem = *(const float2*)&tool_semantics[(size_t)(tok0 + tok) * HIDDEN + c];
        float2 r;
        r.x = sem.x + acc2[tok].x + bias2.x;
        r.y = sem.y + acc2[tok].y + bias2.y;
        *(float2*)&combined[(size_t)(tok0 + tok) * HIDDEN + c] = r;
    }
}

// ---------------------------------------------------------------------------
// Kernel B: out[row][:] = (id >= new_start) ? combined[rel][:] : emb[id][:]
// Grid: B*S blocks; block = 256 threads; each thread moves 4 x float4 = 64 B.
// Loads batched before stores (4 VMEM in flight); stores are non-temporal so
// the 256 MiB write stream does not evict the emb-row gather set from L2/L3.
// ---------------------------------------------------------------------------
__global__ __launch_bounds__(256) void gather_rows_kernel(
    const int* __restrict__ input_ids,      // [B*S]
    const float* __restrict__ emb_weight,   // [VOCAB+NUM_NEW, HIDDEN]
    const float* __restrict__ combined,     // [NUM_NEW, HIDDEN]
    const int* __restrict__ new_start_ptr,  // [1]
    float* __restrict__ out)                // [B*S, HIDDEN]
{
    const int row       = blockIdx.x;
    const int id        = input_ids[row];        // uniform per block
    const int new_start = *new_start_ptr;

    const float* src;
    if (id >= new_start) {
        int rel = id - new_start;
        if (rel > NUM_NEW - 1) rel = NUM_NEW - 1;  // match jnp.clip
        src = combined + (size_t)rel * HIDDEN;
    } else {
        src = emb_weight + (size_t)id * HIDDEN;
    }

    const f32x4* s = (const f32x4*)src;
    f32x4*       d = (f32x4*)(out + (size_t)row * HIDDEN);
    const int t = threadIdx.x;

    // HIDDEN/4 = 1024 float4 slots; 256 threads -> 4 each.
    f32x4 v0 = s[t];
    f32x4 v1 = s[t + 256];
    f32x4 v2 = s[t + 512];
    f32x4 v3 = s[t + 768];
    __builtin_nontemporal_store(v0, d + t);
    __builtin_nontemporal_store(v1, d + t + 256);
    __builtin_nontemporal_store(v2, d + t + 512);
    __builtin_nontemporal_store(v3, d + t + 768);
}

extern "C" void kernel_launch(void* const* d_in, const int* in_sizes, int n_in,
                              void* d_out, int out_size, void* d_ws, size_t ws_size,
                              hipStream_t stream) {
    const int*   input_ids      = (const int*)d_in[0];
    const float* emb_weight     = (const float*)d_in[1];
    const float* tool_semantics = (const float*)d_in[2];
    const float* profiles       = (const float*)d_in[3];
    const float* W1             = (const float*)d_in[4];
    const float* b1             = (const float*)d_in[5];
    const float* W2             = (const float*)d_in[6];
    const float* b2             = (const float*)d_in[7];
    const int*   new_start_ptr  = (const int*)d_in[8];
    float*       out            = (float*)d_out;

    const int num_rows = in_sizes[0];  // B*S = 16384

    // Workspace: combined[NUM_NEW][HIDDEN] f32 = 8 MiB at d_ws offset 0.
    float* combined = (float*)d_ws;

    dim3 gridA(HIDDEN / COLS_PER_BLK, NUM_NEW / TOK_PER_BLK);  // (8, 64)
    build_combined_kernel<<<gridA, 256, 0, stream>>>(
        tool_semantics, profiles, W1, b1, W2, b2, combined);

    gather_rows_kernel<<<num_rows, 256, 0, stream>>>(
        input_ids, emb_weight, combined, new_start_ptr, out);
}